// Round 12
// baseline (173.650 us; speedup 1.0000x reference)
//
#include <hip/hip_runtime.h>
#include <hip/hip_bf16.h>

#define B_ 4
#define S_ 4096
#define DM 1024
#define H_ 16
#define HD 64
#define BH (B_*H_)

typedef __attribute__((ext_vector_type(8))) __bf16 bf16x8;
typedef __attribute__((ext_vector_type(4))) __bf16 bf16x4;
typedef __attribute__((ext_vector_type(4))) float f32x4;

#define MFMA16(a,b,c) __builtin_amdgcn_mfma_f32_16x16x32_bf16((a),(b),(c),0,0,0)

__device__ __forceinline__ void gload_lds16(const void* g, void* l) {
  __builtin_amdgcn_global_load_lds(
      (const __attribute__((address_space(1))) void*)g,
      (__attribute__((address_space(3))) void*)l, 16, 0, 0);
}

// ---------------------------------------------------------------------------
// K1 v7: CONTIGUOUS-READ KV. Block = (b, 64-row s-chunk), ALL 16 heads.
// Streams whole 4-KB rows (1 KB/wave/instr) -> no strided-channel collapse,
// no cross-block duplication. 512 thr = 16 head-groups x 32. f32 VALU outer
// product (inputs unrounded). Split d/e thread tiles => all LDS reads <=2-way.
// Double-buffered gload_lds staging with counted vmcnt(8).
// partial[bh][sc][d*64+e] in bf16. grid = 4*64 = 256 (1 block/CU, 8 waves).
// ---------------------------------------------------------------------------
__global__ __launch_bounds__(512, 2)
void k1_kv(const float* __restrict__ Kg, const float* __restrict__ Vg,
           __bf16* __restrict__ partial) {
  __shared__ __align__(16) float Kb[2][8 * 1024];   // 2 x 32 KiB
  __shared__ __align__(16) float Vb[2][8 * 1024];   // 2 x 32 KiB (128 KiB total)
  const int bid = blockIdx.x;
  const int b = bid >> 6, sc = bid & 63;
  const int t = threadIdx.x, wid = t >> 6;
  const size_t base = ((size_t)b * S_ + sc * 64) * DM;
  const float* Ksrc = Kg + base;
  const float* Vsrc = Vg + base;
  const int g = t >> 5, q = t & 31, dT = q >> 2, eT = q & 3;

  float acc[8][16] = {};

  auto stage = [&](int bi, int st) {
    const float* Kp = Ksrc + (size_t)st * (8 * DM);
    const float* Vp = Vsrc + (size_t)st * (8 * DM);
#pragma unroll
    for (int it = 0; it < 4; ++it) {
      const int idx = it * 512 + t;                  // 2048 granules = 32 KiB
      const int ldso = (it * 512 + wid * 64) * 16;   // wave-uniform base
      gload_lds16((const void*)(Kp + (size_t)idx * 4), (void*)((char*)Kb[bi] + ldso));
      gload_lds16((const void*)(Vp + (size_t)idx * 4), (void*)((char*)Vb[bi] + ldso));
    }
  };

  stage(0, 0);
  for (int st = 0; st < 8; ++st) {
    const int cur = st & 1;
    if (st < 7) {
      stage(cur ^ 1, st + 1);                        // issue-early (T14)
      asm volatile("s_waitcnt vmcnt(8)" ::: "memory");   // buffer st landed
    } else {
      asm volatile("s_waitcnt vmcnt(0)" ::: "memory");
    }
    __builtin_amdgcn_s_barrier();
    const float* Ks = Kb[cur];
    const float* Vs = Vb[cur];
#pragma unroll
    for (int s = 0; s < 8; ++s) {
      float kv[8], vv[16];
#pragma unroll
      for (int hf = 0; hf < 2; ++hf) {
        f32x4 kk = *reinterpret_cast<const f32x4*>(Ks + s * 1024 + g * 64 + hf * 32 + dT * 4);
        f32x4 v0 = *reinterpret_cast<const f32x4*>(Vs + s * 1024 + g * 64 + hf * 32 + eT * 8);
        f32x4 v1 = *reinterpret_cast<const f32x4*>(Vs + s * 1024 + g * 64 + hf * 32 + eT * 8 + 4);
#pragma unroll
        for (int x = 0; x < 4; ++x) {
          kv[hf * 4 + x] = kk[x];
          vv[hf * 8 + x] = v0[x];
          vv[hf * 8 + 4 + x] = v1[x];
        }
      }
#pragma unroll
      for (int i = 0; i < 8; ++i)
#pragma unroll
        for (int j = 0; j < 16; ++j)
          acc[i][j] = fmaf(kv[i], vv[j], acc[i][j]);
    }
    __builtin_amdgcn_s_barrier();                    // compute done before next overwrite
  }

  // write bf16 partial: d = (i>>2)*32 + dT*4 + (i&3), e = vh*32 + eT*8 + jj
  __bf16* dst = partial + ((((size_t)(b * 16 + g)) * 64 + sc) << 12);
#pragma unroll
  for (int i = 0; i < 8; ++i) {
    const int d = (i >> 2) * 32 + dT * 4 + (i & 3);
#pragma unroll
    for (int vh = 0; vh < 2; ++vh) {
      bf16x8 o;
#pragma unroll
      for (int jj = 0; jj < 8; ++jj) o[jj] = (__bf16)acc[i][vh * 8 + jj];
      *reinterpret_cast<bf16x8*>(dst + d * 64 + vh * 32 + eT * 8) = o;
    }
  }
}

// ---------------------------------------------------------------------------
// K2a: partial2[bh][scq][4096] (f32) = sum of 16 bf16 partial chunks.
// grid = 64 bh x 4 scq = 256 blocks. Each block reads 128 KiB CONTIGUOUS.
// ---------------------------------------------------------------------------
__global__ __launch_bounds__(256)
void k2a(const __bf16* __restrict__ partial, float* __restrict__ partial2) {
  const int bid = blockIdx.x;
  const int bh = bid >> 2, scq = bid & 3;
  const int t = threadIdx.x;
  const __bf16* src = partial + ((size_t)bh << 18) + ((size_t)scq << 16);
  float acc[16] = {};
#pragma unroll 4
  for (int sc = 0; sc < 16; ++sc) {
    const __bf16* p = src + (size_t)sc * 4096 + t * 16;
    bf16x8 a0 = *reinterpret_cast<const bf16x8*>(p);
    bf16x8 a1 = *reinterpret_cast<const bf16x8*>(p + 8);
#pragma unroll
    for (int j = 0; j < 8; ++j) { acc[j] += (float)a0[j]; acc[8 + j] += (float)a1[j]; }
  }
  float* dst = partial2 + (((size_t)bh * 4 + scq) << 12) + t * 16;
#pragma unroll
  for (int c = 0; c < 4; ++c) {
    f32x4 o;
#pragma unroll
    for (int j = 0; j < 4; ++j) o[j] = acc[c * 4 + j];
    *reinterpret_cast<f32x4*>(dst + c * 4) = o;
  }
}

// ---------------------------------------------------------------------------
// K2b: kvt[bh][4096] bf16 = sum of 4 f32 partial2 chunks. grid = 256 blocks.
// ---------------------------------------------------------------------------
__global__ __launch_bounds__(256)
void k2b(const float* __restrict__ partial2, __bf16* __restrict__ kvt) {
  const int bid = blockIdx.x;
  const int bh = bid >> 2, eq = bid & 3;
  const int t = threadIdx.x;
  const float* src = partial2 + ((size_t)bh << 14) + eq * 1024 + t * 4;
  f32x4 s = {};
#pragma unroll
  for (int scq = 0; scq < 4; ++scq) {
    f32x4 v = *reinterpret_cast<const f32x4*>(src + (size_t)scq * 4096);
#pragma unroll
    for (int j = 0; j < 4; ++j) s[j] += v[j];
  }
  bf16x4 o;
#pragma unroll
  for (int j = 0; j < 4; ++j) o[j] = (__bf16)s[j];
  *reinterpret_cast<bf16x4*>(kvt + ((size_t)bh << 12) + eq * 1024 + t * 4) = o;
}

// ---------------------------------------------------------------------------
// K2.5: Ut[b][n][h*64+d] = sum_e W[n][h*64+e]*KV[bh][d][e]  (unchanged)
// ---------------------------------------------------------------------------
__global__ __launch_bounds__(256)
void k25_u(const float* __restrict__ Wg,
           const __bf16* __restrict__ kvt,
           __bf16* __restrict__ Ut) {
  const int bid = blockIdx.x;
  const int bh = bid >> 2, nblk = bid & 3;
  const int b = bh >> 4, h = bh & 15;
  const int t = threadIdx.x, w = t >> 6, l = t & 63, lr = l & 15, lg = l >> 4;
  const int n0w = nblk * 256 + w * 64;
  const __bf16* kvb = kvt + ((size_t)bh << 12);
  f32x4 acc[4][4] = {};
#pragma unroll
  for (int ks = 0; ks < 2; ++ks) {
    bf16x8 bfr[4];
#pragma unroll
    for (int nf = 0; nf < 4; ++nf)
      bfr[nf] = *reinterpret_cast<const bf16x8*>(kvb + (nf * 16 + lr) * 64 + ks * 32 + lg * 8);
#pragma unroll
    for (int mf = 0; mf < 4; ++mf) {
      const int n = n0w + mf * 16 + lr;
      const float* wp = Wg + (size_t)n * DM + h * 64 + ks * 32 + lg * 8;
      f32x4 w0 = *reinterpret_cast<const f32x4*>(wp);
      f32x4 w1 = *reinterpret_cast<const f32x4*>(wp + 4);
      bf16x8 af;
#pragma unroll
      for (int j = 0; j < 4; ++j) { af[j] = (__bf16)w0[j]; af[4 + j] = (__bf16)w1[j]; }
#pragma unroll
      for (int nf = 0; nf < 4; ++nf)
        acc[mf][nf] = MFMA16(af, bfr[nf], acc[mf][nf]);
    }
  }
  __bf16* ub = Ut + ((size_t)b << 20);
#pragma unroll
  for (int mf = 0; mf < 4; ++mf)
#pragma unroll
    for (int nf = 0; nf < 4; ++nf)
#pragma unroll
      for (int r = 0; r < 4; ++r) {
        const int n = n0w + mf * 16 + lg * 4 + r;
        ub[(size_t)n * DM + h * 64 + nf * 16 + lr] = (__bf16)acc[mf][nf][r];
      }
}

// ---------------------------------------------------------------------------
// K0q: Q f32 -> bf16 streaming cast (writes ws@0, aliasing dead partial).
// ---------------------------------------------------------------------------
__global__ __launch_bounds__(256)
void k0_convq(const float* __restrict__ Qg, __bf16* __restrict__ Qb) {
  const size_t t = (size_t)blockIdx.x * 256 + threadIdx.x;
#pragma unroll
  for (int it = 0; it < 4; ++it) {
    const size_t i = (size_t)it * 1048576 + t;
    f32x4 w = *reinterpret_cast<const f32x4*>(Qg + i * 4);
    bf16x4 o;
#pragma unroll
    for (int j = 0; j < 4; ++j) o[j] = (__bf16)w[j];
    *reinterpret_cast<bf16x4*>(Qb + i * 4) = o;
  }
}

// ---------------------------------------------------------------------------
// K4 v3: 256x256 tile, 8 waves, 512 thr, BK=64, double-buffered 128 KB LDS,
// phase-split K-step, issue-early full-tile prefetch. (unchanged)
// ---------------------------------------------------------------------------
#define K4_LOAD_A(AF, MH, KS, ACP)                                             \
  _Pragma("unroll")                                                            \
  for (int i_ = 0; i_ < 4; ++i_) {                                             \
    const int row_ = wr * 128 + ((MH) * 4 + i_) * 16 + lr;                     \
    const int ch_ = ((KS) * 4 + lg) ^ (row_ & 7);                              \
    AF[i_] = *reinterpret_cast<const bf16x8*>((ACP) + row_ * 64 + ch_ * 8);    \
  }

#define K4_LOAD_B(BG, KS, BCP)                                                 \
  _Pragma("unroll")                                                            \
  for (int n_ = 0; n_ < 4; ++n_) {                                             \
    const int row_ = wc * 64 + n_ * 16 + lr;                                   \
    const int ch_ = ((KS) * 4 + lg) ^ (row_ & 7);                              \
    BG[n_] = *reinterpret_cast<const bf16x8*>((BCP) + row_ * 64 + ch_ * 8);    \
  }

#define K4_MFMA(AF, BG, MH)                                                    \
  __builtin_amdgcn_s_setprio(1);                                               \
  _Pragma("unroll")                                                            \
  for (int i_ = 0; i_ < 4; ++i_)                                               \
    _Pragma("unroll")                                                          \
    for (int n_ = 0; n_ < 4; ++n_)                                             \
      acc[(MH) * 4 + i_][n_] = MFMA16(AF[i_], BG[n_], acc[(MH) * 4 + i_][n_]); \
  __builtin_amdgcn_s_setprio(0);

__global__ __launch_bounds__(512, 2)
void k4_gemm256(const __bf16* __restrict__ Qb,
                const __bf16* __restrict__ Ut,
                const float* __restrict__ biasg,
                float* __restrict__ outg) {
  __shared__ __align__(16) __bf16 Al0[256 * 64];
  __shared__ __align__(16) __bf16 Al1[256 * 64];
  __shared__ __align__(16) __bf16 Bl0[256 * 64];
  __shared__ __align__(16) __bf16 Bl1[256 * 64];
  const int bid = blockIdx.x;
  const int b = bid >> 6, rem = bid & 63;
  const int mblk = rem & 15, nblk = rem >> 4;
  const int m0 = mblk * 256, n0 = nblk * 256;
  const int t = threadIdx.x;
  const int wid = t >> 6, l = t & 63, lr = l & 15, lg = l >> 4;
  const int wr = wid >> 2, wc = wid & 3;
  const __bf16* Ab = Qb + (size_t)b * S_ * DM;
  const __bf16* Bb = Ut + ((size_t)b << 20);
  f32x4 acc[8][4] = {};

  auto stage_tile = [&](__bf16* Ad, __bf16* Bd, int kt) {
    const int k0 = kt * 64;
#pragma unroll
    for (int ci = 0; ci < 4; ++ci) {
      const int idx = ci * 512 + t;
      const int row = idx >> 3, c = idx & 7;
      const int gc = c ^ (row & 7);
      const int ldso = (ci * 512 + wid * 64) * 16;
      gload_lds16((const void*)(Ab + (size_t)(m0 + row) * DM + k0 + gc * 8),
                  (void*)((char*)Ad + ldso));
      gload_lds16((const void*)(Bb + (size_t)(n0 + row) * DM + k0 + gc * 8),
                  (void*)((char*)Bd + ldso));
    }
  };

  stage_tile(Al0, Bl0, 0);
  for (int kt = 0; kt < 16; ++kt) {
    const int cur = kt & 1;
    asm volatile("s_waitcnt vmcnt(0)" ::: "memory");
    __builtin_amdgcn_s_barrier();
    if (kt < 15) {
      if (cur) stage_tile(Al0, Bl0, kt + 1);
      else     stage_tile(Al1, Bl1, kt + 1);
    }
    const __bf16* Ac = cur ? Al1 : Al0;
    const __bf16* Bc = cur ? Bl1 : Bl0;
    bf16x8 af[4], bg[4];
    K4_LOAD_B(bg, 0, Bc);
    K4_LOAD_A(af, 0, 0, Ac);
    K4_MFMA(af, bg, 0);
    __builtin_amdgcn_s_barrier();
    K4_LOAD_A(af, 1, 0, Ac);
    K4_MFMA(af, bg, 1);
    __builtin_amdgcn_s_barrier();
    K4_LOAD_B(bg, 1, Bc);
    K4_LOAD_A(af, 0, 1, Ac);
    K4_MFMA(af, bg, 0);
    __builtin_amdgcn_s_barrier();
    K4_LOAD_A(af, 1, 1, Ac);
    K4_MFMA(af, bg, 1);
  }

#pragma unroll
  for (int nf = 0; nf < 4; ++nf) {
    const int colg = n0 + wc * 64 + nf * 16 + lr;
    const float bv = biasg[colg];
#pragma unroll
    for (int mf = 0; mf < 8; ++mf)
#pragma unroll
      for (int r = 0; r < 4; ++r) {
        const int rowg = m0 + wr * 128 + mf * 16 + lg * 4 + r;
        outg[((size_t)b * S_ + rowg) * DM + colg] = acc[mf][nf][r] + bv;
      }
  }
}

extern "C" void kernel_launch(void* const* d_in, const int* in_sizes, int n_in,
                              void* d_out, int out_size, void* d_ws, size_t ws_size,
                              hipStream_t stream) {
  const float* Q = (const float*)d_in[0];
  const float* K = (const float*)d_in[1];
  const float* V = (const float*)d_in[2];
  const float* W = (const float*)d_in[3];
  const float* bias = (const float*)d_in[4];
  float* out = (float*)d_out;

  char* ws = (char*)d_ws;
  __bf16* partial = (__bf16*)ws;                      // 32 MiB @0 (k1->k2a)
  __bf16* Qb = (__bf16*)ws;                           // aliases partial (after k2a)
  __bf16* kvt = (__bf16*)(ws + (32u << 20));          // 512 KiB
  __bf16* Ut  = (__bf16*)(ws + (32u << 20) + (512u << 10));   // 8 MiB
  float* partial2 = (float*)(ws + (41u << 20));       // 4 MiB  (total 45 MiB)

  hipLaunchKernelGGL(k1_kv, dim3(256), dim3(512), 0, stream, K, V, partial);
  hipLaunchKernelGGL(k2a, dim3(256), dim3(256), 0, stream, partial, partial2);
  hipLaunchKernelGGL(k2b, dim3(256), dim3(256), 0, stream, partial2, kvt);
  hipLaunchKernelGGL(k25_u, dim3(BH * 4), dim3(256), 0, stream, W, kvt, Ut);
  hipLaunchKernelGGL(k0_convq, dim3(4096), dim3(256), 0, stream, Q, Qb);
  hipLaunchKernelGGL(k4_gemm256, dim3(256), dim3(512), 0, stream, Qb, Ut, bias, out);
}